// Round 2
// baseline (664.155 us; speedup 1.0000x reference)
//
#include <hip/hip_runtime.h>

// correlation[b,s] = <q[b,:], sub[b,s,:]>, argmax over s, one-hot output [bz, 256, 1]
// bz=4096, n_support=256, d=128, all fp32. Memory-bound: stream 512MB of feat_sub.
// Roofline: ~518MB / 6.3 TB/s ~= 82 us.

#define NS 256
#define D  128

__global__ __launch_bounds__(256, 8)
void attnmax_kernel(const float* __restrict__ q,    // [bz, D]
                    const float* __restrict__ sub,  // [bz, NS, D]
                    float* __restrict__ out,        // [bz, NS]
                    int bz)
{
    const int tid  = threadIdx.x;
    const int wave = tid >> 6;        // 0..3
    const int lane = tid & 63;
    const int half = lane >> 5;       // 0 or 1
    const int col  = lane & 31;       // which float4 of the 128-elem row

    __shared__ float s_val[4];
    __shared__ int   s_idx[4];
    __shared__ int   s_best;

    for (int b = blockIdx.x; b < bz; b += gridDim.x) {
        // Query fragment for this column (512B per block, broadcast across halves).
        const float4 q4 = reinterpret_cast<const float4*>(q + (size_t)b * D)[col];

        // Wave w covers rows [w*64, w*64+64), 2 rows per iteration
        // (half 0 -> even row, half 1 -> odd row). Each load instruction is a
        // fully-coalesced 1KB segment (64 lanes x float4 spanning 2 rows).
        const float4* base = reinterpret_cast<const float4*>(sub + (size_t)b * NS * D)
                           + (size_t)(wave * 64 + half) * (D / 4) + col;

        float best_val = -INFINITY;
        int   best_idx = 0;

        #pragma unroll 8
        for (int it = 0; it < 32; ++it) {
            const float4 v = base[(size_t)it * 2 * (D / 4)];
            float p = v.x * q4.x + v.y * q4.y + v.z * q4.z + v.w * q4.w;
            // reduce across the 32 lanes of this half (xor<32 stays within half)
            p += __shfl_xor(p, 1);
            p += __shfl_xor(p, 2);
            p += __shfl_xor(p, 4);
            p += __shfl_xor(p, 8);
            p += __shfl_xor(p, 16);
            // ascending s + strict '>' == first-index argmax semantics
            const int s = wave * 64 + it * 2 + half;
            if (p > best_val) { best_val = p; best_idx = s; }
        }

        // Combine the two halves of this wave (smaller idx wins ties).
        {
            const float ov = __shfl_xor(best_val, 32);
            const int   oi = __shfl_xor(best_idx, 32);
            if (ov > best_val || (ov == best_val && oi < best_idx)) {
                best_val = ov; best_idx = oi;
            }
        }

        if (lane == 0) { s_val[wave] = best_val; s_idx[wave] = best_idx; }
        __syncthreads();
        if (tid == 0) {
            float bv = s_val[0]; int bi = s_idx[0];
            #pragma unroll
            for (int w = 1; w < 4; ++w) {
                const float v = s_val[w]; const int i = s_idx[w];
                if (v > bv || (v == bv && i < bi)) { bv = v; bi = i; }
            }
            s_best = bi;
        }
        __syncthreads();

        const int bi = s_best;
        // Coalesced one-hot row write (d_out is poisoned 0xAA -> must write all).
        out[(size_t)b * NS + tid] = (tid == bi) ? 1.0f : 0.0f;
        __syncthreads();  // protect s_* before next batch iteration
    }
}

extern "C" void kernel_launch(void* const* d_in, const int* in_sizes, int n_in,
                              void* d_out, int out_size, void* d_ws, size_t ws_size,
                              hipStream_t stream) {
    const float* q   = (const float*)d_in[0];   // [bz, 128]
    const float* sub = (const float*)d_in[1];   // [bz, 256, 128]
    float* out = (float*)d_out;                 // [bz, 256, 1]

    const int bz = in_sizes[0] / D;             // 4096
    const int grid = bz < 4096 ? bz : 4096;
    attnmax_kernel<<<dim3(grid), dim3(256), 0, stream>>>(q, sub, out, bz);
}

// Round 4
// 647.110 us; speedup vs baseline: 1.0263x; 1.0263x over previous
//
#include <hip/hip_runtime.h>

// correlation[b,s] = <q[b,:], sub[b,s,:]>, argmax over s, one-hot output [bz, 256, 1]
// bz=4096, n_support=256, d=128, all fp32. Memory-bound: stream 512MB of feat_sub.
// Roofline: ~518MB / 6.3 TB/s ~= 82 us. Measured round-2 bench dur 664us includes
// ~335us of harness d_ws poison + ~240-320us d_in restore (kernel itself <331us
// per rocprof top-5 bound).

#define NS 256
#define D  128

typedef float v4f __attribute__((ext_vector_type(4)));

__global__ __launch_bounds__(256, 4)   // VGPR cap 128: room for 8 in-flight float4 loads, no spills
void attnmax_kernel(const float* __restrict__ q,    // [bz, D]
                    const float* __restrict__ sub,  // [bz, NS, D]
                    float* __restrict__ out,        // [bz, NS]
                    int bz)
{
    const int tid  = threadIdx.x;
    const int wave = tid >> 6;        // 0..3
    const int lane = tid & 63;
    const int half = lane >> 5;       // 0 or 1
    const int col  = lane & 31;       // which float4 of the 128-elem row

    __shared__ float s_val[4];
    __shared__ int   s_idx[4];
    __shared__ int   s_best;

    for (int b = blockIdx.x; b < bz; b += gridDim.x) {
        // Query fragment for this column (512B per block, broadcast across halves).
        const v4f q4 = reinterpret_cast<const v4f*>(q + (size_t)b * D)[col];

        // Wave w covers rows [w*64, w*64+64), 2 rows per iteration
        // (half 0 -> even row, half 1 -> odd row). Each load instruction is a
        // fully-coalesced 1KB segment (64 lanes x float4 spanning 2 rows).
        const v4f* base = reinterpret_cast<const v4f*>(sub + (size_t)b * NS * D)
                        + (size_t)(wave * 64 + half) * (D / 4) + col;

        float best_val = -INFINITY;
        int   best_idx = 0;

        #pragma unroll 8
        for (int it = 0; it < 32; ++it) {
            // Non-temporal: 512MB streamed once, zero reuse — don't thrash L2.
            const v4f v = __builtin_nontemporal_load(base + (size_t)it * 2 * (D / 4));
            float p = v[0] * q4[0] + v[1] * q4[1] + v[2] * q4[2] + v[3] * q4[3];
            // reduce across the 32 lanes of this half (xor<32 stays within half)
            p += __shfl_xor(p, 1);
            p += __shfl_xor(p, 2);
            p += __shfl_xor(p, 4);
            p += __shfl_xor(p, 8);
            p += __shfl_xor(p, 16);
            // ascending s + strict '>' == first-index argmax semantics
            const int s = wave * 64 + it * 2 + half;
            if (p > best_val) { best_val = p; best_idx = s; }
        }

        // Combine the two halves of this wave (smaller idx wins ties).
        {
            const float ov = __shfl_xor(best_val, 32);
            const int   oi = __shfl_xor(best_idx, 32);
            if (ov > best_val || (ov == best_val && oi < best_idx)) {
                best_val = ov; best_idx = oi;
            }
        }

        if (lane == 0) { s_val[wave] = best_val; s_idx[wave] = best_idx; }
        __syncthreads();
        if (tid == 0) {
            float bv = s_val[0]; int bi = s_idx[0];
            #pragma unroll
            for (int w = 1; w < 4; ++w) {
                const float v = s_val[w]; const int i = s_idx[w];
                if (v > bv || (v == bv && i < bi)) { bv = v; bi = i; }
            }
            s_best = bi;
        }
        __syncthreads();

        const int bi = s_best;
        // Coalesced one-hot row write (d_out is poisoned 0xAA -> must write all).
        out[(size_t)b * NS + tid] = (tid == bi) ? 1.0f : 0.0f;
        __syncthreads();  // protect s_* before next batch iteration
    }
}

extern "C" void kernel_launch(void* const* d_in, const int* in_sizes, int n_in,
                              void* d_out, int out_size, void* d_ws, size_t ws_size,
                              hipStream_t stream) {
    const float* q   = (const float*)d_in[0];   // [bz, 128]
    const float* sub = (const float*)d_in[1];   // [bz, 256, 128]
    float* out = (float*)d_out;                 // [bz, 256, 1]

    const int bz = in_sizes[0] / D;             // 4096
    const int grid = bz < 4096 ? bz : 4096;
    attnmax_kernel<<<dim3(grid), dim3(256), 0, stream>>>(q, sub, out, bz);
}